// Round 10
// baseline (336.515 us; speedup 1.0000x reference)
//
#include <hip/hip_runtime.h>

typedef unsigned short ushort_t;
typedef unsigned int uint_t;

typedef __bf16 bf16x8 __attribute__((ext_vector_type(8)));
typedef float f32x4 __attribute__((ext_vector_type(4)));

static __device__ __forceinline__ float bf2f(ushort_t h) {
    return __uint_as_float(((uint_t)h) << 16);
}
static __device__ __forceinline__ ushort_t f2bf(float f) {
    uint_t u = __float_as_uint(f);
    u = u + 0x7FFFu + ((u >> 16) & 1u);
    return (ushort_t)(u >> 16);
}
// pack two floats as bf16 (round-half-up) into one dword: low=lo, high=hi
static __device__ __forceinline__ uint_t pkbf(float lo, float hi) {
    uint_t a = __float_as_uint(lo) + 0x8000u;
    uint_t b = __float_as_uint(hi) + 0x8000u;
    return __builtin_amdgcn_perm(b, a, 0x07060302u);
}

// ---------------- constants ----------------
#define BB 32
#define HH 56
#define WW_ 56
#define CC 128
#define NHEAD 4
#define WS 7
#define SS 3
#define LL (HH * WW_)           // 3136
#define NTOK (BB * LL)          // 100352
#define NWIN (BB * 64)          // 2048
#define NN 49
#define HD 32
#define QKS 32                  // Q/K LDS stride (shorts)
#define PLS 40                  // P half stride (shorts), conflict-free
#define VTS 72                  // Vt stride (shorts), conflict-free

// windowed token -> global token (shift map)
static __device__ __forceinline__ int win2tok(int wid) {
    int win = wid / NN, t = wid - win * NN;
    int bb = win >> 6, wrem = win & 63;
    int wi = wrem >> 3, wj = wrem & 7;
    int ti = t / WS, tj = t - ti * WS;
    int hh = wi * WS + ti + SS; if (hh >= HH) hh -= HH;
    int ww = wj * WS + tj + SS; if (ww >= WW_) ww -= WW_;
    return bb * LL + hh * WW_ + ww;
}

// ============ weight pre-convert fp32->bf16 ============
__global__ __launch_bounds__(256) void prep_weights(
    const float* __restrict__ qkv_w, const float* __restrict__ proj_w,
    const float* __restrict__ fc1_w, const float* __restrict__ fc2_w,
    ushort_t* __restrict__ dst) {
    int i = blockIdx.x * 256 + threadIdx.x;   // 0 .. 196607
    const float* src;
    int off;
    if (i < 49152)        { src = qkv_w;  off = i; }
    else if (i < 65536)   { src = proj_w; off = i - 49152; }
    else if (i < 131072)  { src = fc1_w;  off = i - 65536; }
    else                  { src = fc2_w;  off = i - 131072; }
    dst[i] = f2bf(src[off]);
}

// ============ bias table: bias[h][i][j] (64x64 padded, fp32) ============
__global__ __launch_bounds__(256) void build_bias(
    const float* __restrict__ rpb, const int* __restrict__ rel_idx,
    float* __restrict__ bias) {
    int h = blockIdx.x;
    for (int idx = threadIdx.x; idx < 4096; idx += 256) {
        int i = idx >> 6, j = idx & 63;
        float v = 0.f;
        if (i < NN && j < NN)
            v = rpb[(size_t)rel_idx[i * NN + j] * NHEAD + h];
        bias[h * 4096 + idx] = v;
    }
}

// ============ MEGA KERNEL: whole Swin block, 1 block = 1 window ============
// LDS: U (32 KB): XLN -> per-head Q/K/P -> O staging -> H2.
//      HVPS (18.4 KB): per-head Vt -> PS (proj out / fc1 P chunks).
// x2 goes through a bf16 global scratch (per-window rows, block-local).
__global__ __launch_bounds__(256, 3) void swin_block(
    const float* __restrict__ x, const float* __restrict__ g1,
    const float* __restrict__ b1, const ushort_t* __restrict__ wq,
    const float* __restrict__ qkv_b, const float* __restrict__ bias,
    const ushort_t* __restrict__ wp, const float* __restrict__ proj_b,
    const float* __restrict__ g2, const float* __restrict__ b2,
    const ushort_t* __restrict__ w1, const float* __restrict__ b1f,
    const ushort_t* __restrict__ w2, const float* __restrict__ b2f,
    ushort_t* __restrict__ x2s, float* __restrict__ out, int win0) {
    __shared__ __align__(16) ushort_t U[16384];      // 32768 B
    __shared__ __align__(16) ushort_t HVPS[9216];    // 18432 B
    const int tid = threadIdx.x;
    const int wave = tid >> 6;          // head
    const int lane = tid & 63;
    const int l16 = lane & 15;
    const int quad = lane >> 4;
    const int h = wave;
    const int win = win0 + blockIdx.x;
    const float scale = 0.17677669529663687f;   // 32^-0.5

    ushort_t* XLN = U;                         // 64 x 136
    ushort_t* QL = U + h * 4096;               // 64 x 32
    ushort_t* KL = QL + 2048;                  // 64 x 32
    ushort_t* PL = QL;                         // 64 x 40 overlay (own wave)
    ushort_t* VT = HVPS + h * 2304;            // 32 x 72
    ushort_t* OS = U;                          // 64 x 136 (O staging, then H2)
    ushort_t* AH = U;                          // H2
    ushort_t* PS = HVPS;                       // 64 x 136

    // ---- LN1 (4 threads/row; rows >=49 clamped to token 0) ----
    {
        int row = tid >> 2;
        int ch0 = (tid & 3) * 32;
        int t = (row < NN) ? row : 0;
        int gtok = win2tok(win * NN + t);
        const float* xp = x + (size_t)gtok * CC + ch0;
        float v[32];
        float s = 0.f, sq = 0.f;
        #pragma unroll
        for (int i = 0; i < 4; ++i) {
            float4 a0 = *(const float4*)(xp + i * 8);
            float4 a1 = *(const float4*)(xp + i * 8 + 4);
            v[i * 8 + 0] = a0.x; v[i * 8 + 1] = a0.y;
            v[i * 8 + 2] = a0.z; v[i * 8 + 3] = a0.w;
            v[i * 8 + 4] = a1.x; v[i * 8 + 5] = a1.y;
            v[i * 8 + 6] = a1.z; v[i * 8 + 7] = a1.w;
            #pragma unroll
            for (int j = 0; j < 8; ++j) { s += v[i * 8 + j]; sq += v[i * 8 + j] * v[i * 8 + j]; }
        }
        s += __shfl_xor(s, 1);  sq += __shfl_xor(sq, 1);
        s += __shfl_xor(s, 2);  sq += __shfl_xor(sq, 2);
        float mean = s * (1.0f / 128.0f);
        float var = sq * (1.0f / 128.0f) - mean * mean;
        float rstd = rsqrtf(var + 1e-5f);
        #pragma unroll
        for (int i = 0; i < 4; ++i) {
            ushort_t tmp[8];
            #pragma unroll
            for (int j = 0; j < 8; ++j) {
                int c = ch0 + i * 8 + j;
                tmp[j] = f2bf((v[i * 8 + j] - mean) * rstd * g1[c] + b1[c]);
            }
            *(uint4*)&XLN[row * 136 + ch0 + i * 8] = *(const uint4*)tmp;
        }
    }
    __syncthreads();   // B1: XLN ready

    // ---- cache token frags in regs ----
    bf16x8 tf[4][4];
    #pragma unroll
    for (int kk = 0; kk < 4; ++kk)
        #pragma unroll
        for (int i = 0; i < 4; ++i)
            tf[kk][i] = *(const bf16x8*)&XLN[(16 * i + l16) * 136 + kk * 32 + quad * 8];
    __syncthreads();   // B2: XLN dead -> Q/K region

    // ---- Q (swapped), scale folded ----
    {
        f32x4 s1[2][4];
        #pragma unroll
        for (int j = 0; j < 2; ++j)
            #pragma unroll
            for (int i = 0; i < 4; ++i)
                s1[j][i] = (f32x4){0.f, 0.f, 0.f, 0.f};
        #pragma unroll
        for (int kk = 0; kk < 4; ++kk)
            #pragma unroll
            for (int j = 0; j < 2; ++j) {
                bf16x8 wf = *(const bf16x8*)&wq[(size_t)(h * 32 + 16 * j + l16) * 128 + kk * 32 + quad * 8];
                #pragma unroll
                for (int i = 0; i < 4; ++i)
                    s1[j][i] = __builtin_amdgcn_mfma_f32_16x16x32_bf16(wf, tf[kk][i], s1[j][i], 0, 0, 0);
            }
        #pragma unroll
        for (int j = 0; j < 2; ++j) {
            float4 bv = *(const float4*)&qkv_b[h * 32 + 16 * j + quad * 4];
            #pragma unroll
            for (int i = 0; i < 4; ++i) {
                uint2 pk;
                pk.x = pkbf((s1[j][i][0] + bv.x) * scale, (s1[j][i][1] + bv.y) * scale);
                pk.y = pkbf((s1[j][i][2] + bv.z) * scale, (s1[j][i][3] + bv.w) * scale);
                *(uint2*)&QL[(16 * i + l16) * QKS + 16 * j + quad * 4] = pk;
            }
        }
    }
    // ---- K (swapped) ----
    {
        f32x4 s1[2][4];
        #pragma unroll
        for (int j = 0; j < 2; ++j)
            #pragma unroll
            for (int i = 0; i < 4; ++i)
                s1[j][i] = (f32x4){0.f, 0.f, 0.f, 0.f};
        #pragma unroll
        for (int kk = 0; kk < 4; ++kk)
            #pragma unroll
            for (int j = 0; j < 2; ++j) {
                bf16x8 wf = *(const bf16x8*)&wq[(size_t)(128 + h * 32 + 16 * j + l16) * 128 + kk * 32 + quad * 8];
                #pragma unroll
                for (int i = 0; i < 4; ++i)
                    s1[j][i] = __builtin_amdgcn_mfma_f32_16x16x32_bf16(wf, tf[kk][i], s1[j][i], 0, 0, 0);
            }
        #pragma unroll
        for (int j = 0; j < 2; ++j) {
            float4 bv = *(const float4*)&qkv_b[128 + h * 32 + 16 * j + quad * 4];
            #pragma unroll
            for (int i = 0; i < 4; ++i) {
                uint2 pk;
                pk.x = pkbf(s1[j][i][0] + bv.x, s1[j][i][1] + bv.y);
                pk.y = pkbf(s1[j][i][2] + bv.z, s1[j][i][3] + bv.w);
                *(uint2*)&KL[(16 * i + l16) * QKS + 16 * j + quad * 4] = pk;
            }
        }
    }
    // ---- V (non-swapped -> Vt[d][token]) ----
    {
        f32x4 sv[4][2];
        #pragma unroll
        for (int i = 0; i < 4; ++i)
            #pragma unroll
            for (int j = 0; j < 2; ++j)
                sv[i][j] = (f32x4){0.f, 0.f, 0.f, 0.f};
        #pragma unroll
        for (int kk = 0; kk < 4; ++kk)
            #pragma unroll
            for (int j = 0; j < 2; ++j) {
                bf16x8 wf = *(const bf16x8*)&wq[(size_t)(256 + h * 32 + 16 * j + l16) * 128 + kk * 32 + quad * 8];
                #pragma unroll
                for (int i = 0; i < 4; ++i)
                    sv[i][j] = __builtin_amdgcn_mfma_f32_16x16x32_bf16(tf[kk][i], wf, sv[i][j], 0, 0, 0);
            }
        #pragma unroll
        for (int j = 0; j < 2; ++j) {
            float bvv = qkv_b[256 + h * 32 + 16 * j + l16];
            #pragma unroll
            for (int i = 0; i < 4; ++i) {
                uint2 pk;
                pk.x = pkbf(sv[i][j][0] + bvv, sv[i][j][1] + bvv);
                pk.y = pkbf(sv[i][j][2] + bvv, sv[i][j][3] + bvv);
                *(uint2*)&VT[(16 * j + l16) * VTS + 16 * i + quad * 4] = pk;
            }
        }
    }

    // ---- S = QK^T ----
    f32x4 s[4][4];
    {
        bf16x8 qa[4], kb[4];
        #pragma unroll
        for (int t = 0; t < 4; ++t) {
            qa[t] = *(const bf16x8*)&QL[(16 * t + l16) * QKS + quad * 8];
            kb[t] = *(const bf16x8*)&KL[(16 * t + l16) * QKS + quad * 8];
        }
        #pragma unroll
        for (int mi = 0; mi < 4; ++mi)
            #pragma unroll
            for (int ni = 0; ni < 4; ++ni) {
                f32x4 z = {0.f, 0.f, 0.f, 0.f};
                s[mi][ni] = __builtin_amdgcn_mfma_f32_16x16x32_bf16(qa[mi], kb[ni], z, 0, 0, 0);
            }
    }
    // ---- + rpb bias ----
    const float* bh = bias + h * 4096;
    #pragma unroll
    for (int mi = 0; mi < 4; ++mi)
        #pragma unroll
        for (int ni = 0; ni < 4; ++ni)
            #pragma unroll
            for (int r = 0; r < 4; ++r)
                s[mi][ni][r] += bh[(16 * mi + quad * 4 + r) * 64 + 16 * ni + l16];
    // ---- softmax (cols >=49 masked) ----
    #pragma unroll
    for (int mi = 0; mi < 4; ++mi)
        #pragma unroll
        for (int r = 0; r < 4; ++r) {
            float m01 = fmaxf(s[mi][0][r], s[mi][1][r]);
            float m2 = s[mi][2][r];
            float m3 = (l16 == 0) ? s[mi][3][r] : -3.0e38f;
            float mx = fmaxf(fmaxf(m01, m2), m3);
            mx = fmaxf(mx, __shfl_xor(mx, 1));
            mx = fmaxf(mx, __shfl_xor(mx, 2));
            mx = fmaxf(mx, __shfl_xor(mx, 4));
            mx = fmaxf(mx, __shfl_xor(mx, 8));
            float e0 = expf(s[mi][0][r] - mx);
            float e1 = expf(s[mi][1][r] - mx);
            float e2 = expf(s[mi][2][r] - mx);
            float e3 = (l16 == 0) ? expf(s[mi][3][r] - mx) : 0.f;
            float sum = (e0 + e1) + (e2 + e3);
            sum += __shfl_xor(sum, 1);
            sum += __shfl_xor(sum, 2);
            sum += __shfl_xor(sum, 4);
            sum += __shfl_xor(sum, 8);
            float inv = 1.0f / sum;
            s[mi][0][r] = e0 * inv;
            s[mi][1][r] = e1 * inv;
            s[mi][2][r] = e2 * inv;
            s[mi][3][r] = e3 * inv;
        }

    // ---- O^T = Vt · P^T, P streamed in two halves through PL ----
    f32x4 o[2][4];
    #pragma unroll
    for (int it = 0; it < 2; ++it)
        #pragma unroll
        for (int jt = 0; jt < 4; ++jt)
            o[it][jt] = (f32x4){0.f, 0.f, 0.f, 0.f};
    #pragma unroll
    for (int k0 = 0; k0 < 64; k0 += 32) {
        int nb = k0 >> 4;
        #pragma unroll
        for (int mi = 0; mi < 4; ++mi)
            #pragma unroll
            for (int nn = 0; nn < 2; ++nn)
                #pragma unroll
                for (int r = 0; r < 4; ++r)
                    PL[(16 * mi + quad * 4 + r) * PLS + 16 * nn + l16] = f2bf(s[mi][nb + nn][r]);
        bf16x8 va[2], pb[4];
        #pragma unroll
        for (int it = 0; it < 2; ++it)
            va[it] = *(const bf16x8*)&VT[(16 * it + l16) * VTS + k0 + quad * 8];
        #pragma unroll
        for (int jt = 0; jt < 4; ++jt)
            pb[jt] = *(const bf16x8*)&PL[(16 * jt + l16) * PLS + quad * 8];
        #pragma unroll
        for (int it = 0; it < 2; ++it)
            #pragma unroll
            for (int jt = 0; jt < 4; ++jt)
                o[it][jt] = __builtin_amdgcn_mfma_f32_16x16x32_bf16(va[it], pb[jt], o[it][jt], 0, 0, 0);
    }
    __syncthreads();   // B3: all Q/K/P reads done -> U becomes O staging

    // ---- O -> LDS (all 64 rows; padded rows finite) ----
    #pragma unroll
    for (int jt = 0; jt < 4; ++jt) {
        int m = 16 * jt + l16;
        #pragma unroll
        for (int it = 0; it < 2; ++it) {
            ushort4 st;
            st.x = f2bf(o[it][jt][0]);
            st.y = f2bf(o[it][jt][1]);
            st.z = f2bf(o[it][jt][2]);
            st.w = f2bf(o[it][jt][3]);
            *(ushort4*)&OS[m * 136 + h * HD + 16 * it + quad * 4] = st;
        }
    }
    __syncthreads();   // B4: O ready (Vt dead -> PS region free)

    // ---- proj (swapped): PS[token][projcol] ----
    {
        f32x4 pa[2][4];
        #pragma unroll
        for (int j = 0; j < 2; ++j)
            #pragma unroll
            for (int i = 0; i < 4; ++i)
                pa[j][i] = (f32x4){0.f, 0.f, 0.f, 0.f};
        const int wn = wave * 32;
        #pragma unroll
        for (int kk = 0; kk < 4; ++kk) {
            bf16x8 af[4];
            #pragma unroll
            for (int i = 0; i < 4; ++i)
                af[i] = *(const bf16x8*)&OS[(16 * i + l16) * 136 + kk * 32 + quad * 8];
            #pragma unroll
            for (int j = 0; j < 2; ++j) {
                bf16x8 wf = *(const bf16x8*)&wp[(size_t)(wn + 16 * j + l16) * 128 + kk * 32 + quad * 8];
                #pragma unroll
                for (int i = 0; i < 4; ++i)
                    pa[j][i] = __builtin_amdgcn_mfma_f32_16x16x32_bf16(wf, af[i], pa[j][i], 0, 0, 0);
            }
        }
        #pragma unroll
        for (int j = 0; j < 2; ++j) {
            float4 bv = *(const float4*)&proj_b[wn + 16 * j + quad * 4];
            #pragma unroll
            for (int i = 0; i < 4; ++i) {
                uint2 pk;
                pk.x = pkbf(pa[j][i][0] + bv.x, pa[j][i][1] + bv.y);
                pk.y = pkbf(pa[j][i][2] + bv.z, pa[j][i][3] + bv.w);
                *(uint2*)&PS[(16 * i + l16) * 136 + wn + 16 * j + quad * 4] = pk;
            }
        }
    }
    __syncthreads();   // B5: PS ready, OS reads done -> U becomes H2

    // ---- residual + LN2: x2 -> scratch (bf16), h2 -> AH ----
    {
        int row = tid >> 2;
        int ch0 = (tid & 3) * 32;
        int t = (row < NN) ? row : 0;
        int gtok = win2tok(win * NN + t);
        const float* xp = x + (size_t)gtok * CC + ch0;
        float v[32];
        float s2 = 0.f, sq = 0.f;
        #pragma unroll
        for (int i = 0; i < 4; ++i) {
            float4 a0 = *(const float4*)(xp + i * 8);
            float4 a1 = *(const float4*)(xp + i * 8 + 4);
            ushort4 p0 = *(const ushort4*)&PS[row * 136 + ch0 + i * 8];
            ushort4 p1 = *(const ushort4*)&PS[row * 136 + ch0 + i * 8 + 4];
            v[i * 8 + 0] = a0.x + bf2f(p0.x); v[i * 8 + 1] = a0.y + bf2f(p0.y);
            v[i * 8 + 2] = a0.z + bf2f(p0.z); v[i * 8 + 3] = a0.w + bf2f(p0.w);
            v[i * 8 + 4] = a1.x + bf2f(p1.x); v[i * 8 + 5] = a1.y + bf2f(p1.y);
            v[i * 8 + 6] = a1.z + bf2f(p1.z); v[i * 8 + 7] = a1.w + bf2f(p1.w);
            #pragma unroll
            for (int j = 0; j < 8; ++j) { s2 += v[i * 8 + j]; sq += v[i * 8 + j] * v[i * 8 + j]; }
        }
        // x2 -> global scratch (bf16), block-local rows
        #pragma unroll
        for (int i = 0; i < 4; ++i) {
            ushort_t tmp[8];
            #pragma unroll
            for (int j = 0; j < 8; ++j) tmp[j] = f2bf(v[i * 8 + j]);
            *(uint4*)&x2s[((size_t)(blockIdx.x * 64 + row)) * CC + ch0 + i * 8] = *(const uint4*)tmp;
        }
        s2 += __shfl_xor(s2, 1);  sq += __shfl_xor(sq, 1);
        s2 += __shfl_xor(s2, 2);  sq += __shfl_xor(sq, 2);
        float mean = s2 * (1.0f / 128.0f);
        float var = sq * (1.0f / 128.0f) - mean * mean;
        float rstd = rsqrtf(var + 1e-5f);
        #pragma unroll
        for (int i = 0; i < 4; ++i) {
            ushort_t tmp[8];
            #pragma unroll
            for (int j = 0; j < 8; ++j) {
                int c = ch0 + i * 8 + j;
                tmp[j] = f2bf((v[i * 8 + j] - mean) * rstd * g2[c] + b2[c]);
            }
            *(uint4*)&AH[row * 136 + ch0 + i * 8] = *(const uint4*)tmp;
        }
    }
    __syncthreads();   // B6: H2 ready, PS LN2-reads done

    // ---- MLP: 4 chunks of 128 fc1 cols ----
    f32x4 acc2[2][4];
    #pragma unroll
    for (int j = 0; j < 2; ++j)
        #pragma unroll
        for (int i = 0; i < 4; ++i)
            acc2[j][i] = (f32x4){0.f, 0.f, 0.f, 0.f};
    const int wn = wave * 32;

    for (int c = 0; c < 4; ++c) {
        f32x4 s1[2][4];
        #pragma unroll
        for (int j = 0; j < 2; ++j)
            #pragma unroll
            for (int i = 0; i < 4; ++i)
                s1[j][i] = (f32x4){0.f, 0.f, 0.f, 0.f};
        #pragma unroll
        for (int kk = 0; kk < 4; ++kk) {
            bf16x8 af[4];
            #pragma unroll
            for (int i = 0; i < 4; ++i)
                af[i] = *(const bf16x8*)&AH[(16 * i + l16) * 136 + kk * 32 + quad * 8];
            #pragma unroll
            for (int j = 0; j < 2; ++j) {
                bf16x8 wf = *(const bf16x8*)&w1[(size_t)(c * 128 + wn + 16 * j + l16) * 128 + kk * 32 + quad * 8];
                #pragma unroll
                for (int i = 0; i < 4; ++i)
                    s1[j][i] = __builtin_amdgcn_mfma_f32_16x16x32_bf16(wf, af[i], s1[j][i], 0, 0, 0);
            }
        }
        uint2 pk[2][4];
        #pragma unroll
        for (int j = 0; j < 2; ++j) {
            float4 bv = *(const float4*)&b1f[c * 128 + wn + 16 * j + quad * 4];
            #pragma unroll
            for (int i = 0; i < 4; ++i) {
                float g[4];
                #pragma unroll
                for (int r = 0; r < 4; ++r) {
                    float u = s1[j][i][r] + ((const float*)&bv)[r];
                    float z = 1.5957691216f * u * (1.0f + 0.044715f * u * u);
                    g[r] = u / (1.0f + __expf(-z));
                }
                pk[j][i].x = pkbf(g[0], g[1]);
                pk[j][i].y = pkbf(g[2], g[3]);
            }
        }
        __syncthreads();
        #pragma unroll
        for (int j = 0; j < 2; ++j)
            #pragma unroll
            for (int i = 0; i < 4; ++i)
                *(uint2*)&PS[(16 * i + l16) * 136 + wn + 16 * j + quad * 4] = pk[j][i];
        __syncthreads();
        #pragma unroll
        for (int kk = 0; kk < 4; ++kk) {
            bf16x8 pf[4];
            #pragma unroll
            for (int i = 0; i < 4; ++i)
                pf[i] = *(const bf16x8*)&PS[(16 * i + l16) * 136 + kk * 32 + quad * 8];
            #pragma unroll
            for (int j = 0; j < 2; ++j) {
                bf16x8 wf = *(const bf16x8*)&w2[(size_t)(wn + 16 * j + l16) * 512 + c * 128 + kk * 32 + quad * 8];
                #pragma unroll
                for (int i = 0; i < 4; ++i)
                    acc2[j][i] = __builtin_amdgcn_mfma_f32_16x16x32_bf16(wf, pf[i], acc2[j][i], 0, 0, 0);
            }
        }
    }

    // ---- epilogue: out = x2(scratch) + mlp + bias2 (guarded) ----
    #pragma unroll
    for (int i = 0; i < 4; ++i) {
        int m = 16 * i + l16;
        if (m < NN) {
            int gtok = win2tok(win * NN + m);
            #pragma unroll
            for (int j = 0; j < 2; ++j) {
                float4 bv = *(const float4*)&b2f[wn + 16 * j + quad * 4];
                ushort4 xv = *(const ushort4*)&x2s[((size_t)(blockIdx.x * 64 + m)) * CC + wn + 16 * j + quad * 4];
                float4 cur;
                cur.x = bf2f(xv.x) + acc2[j][i][0] + bv.x;
                cur.y = bf2f(xv.y) + acc2[j][i][1] + bv.y;
                cur.z = bf2f(xv.z) + acc2[j][i][2] + bv.z;
                cur.w = bf2f(xv.w) + acc2[j][i][3] + bv.w;
                *(float4*)(out + (size_t)gtok * CC + wn + 16 * j + quad * 4) = cur;
            }
        }
    }
}

// ============ launch ============
extern "C" void kernel_launch(void* const* d_in, const int* in_sizes, int n_in,
                              void* d_out, int out_size, void* d_ws, size_t ws_size,
                              hipStream_t stream) {
    const float* x       = (const float*)d_in[0];
    const float* norm1_g = (const float*)d_in[1];
    const float* norm1_b = (const float*)d_in[2];
    const float* qkv_w   = (const float*)d_in[3];
    const float* qkv_b   = (const float*)d_in[4];
    const float* rpb     = (const float*)d_in[5];
    const float* proj_w  = (const float*)d_in[6];
    const float* proj_b  = (const float*)d_in[7];
    const float* norm2_g = (const float*)d_in[8];
    const float* norm2_b = (const float*)d_in[9];
    const float* fc1_w   = (const float*)d_in[10];
    const float* fc1_b   = (const float*)d_in[11];
    const float* fc2_w   = (const float*)d_in[12];
    const float* fc2_b   = (const float*)d_in[13];
    const int*   rel_idx = (const int*)d_in[14];

    char* ws = (char*)d_ws;
    float*    biasT = (float*)ws;
    ushort_t* wall  = (ushort_t*)(ws + 65536);
    ushort_t* wqkv  = wall;
    ushort_t* wproj = wall + 49152;
    ushort_t* wfc1  = wall + 65536;
    ushort_t* wfc2  = wall + 131072;
    const size_t base = 524288;
    // chunk windows so x2 scratch fits ws
    int f = 1;
    while (f < 16) {
        size_t szS = (size_t)NWIN * 64 * CC * 2 / f;   // 33.5 MB at f=1
        if (base + szS <= ws_size) break;
        f *= 2;
    }
    int wc = NWIN / f;
    ushort_t* x2s = (ushort_t*)(ws + base);

    prep_weights<<<dim3(768), dim3(256), 0, stream>>>(qkv_w, proj_w, fc1_w, fc2_w, wall);
    build_bias<<<dim3(NHEAD), dim3(256), 0, stream>>>(rpb, rel_idx, biasT);
    for (int c = 0; c < f; ++c) {
        swin_block<<<dim3(wc), dim3(256), 0, stream>>>(
            x, norm1_g, norm1_b, wqkv, qkv_b, biasT, wproj, proj_b,
            norm2_g, norm2_b, wfc1, fc1_b, wfc2, fc2_b,
            x2s, (float*)d_out, c * wc);
    }
}